// Round 5
// baseline (350.333 us; speedup 1.0000x reference)
//
#include <hip/hip_runtime.h>
#include <hip/hip_bf16.h>

#define IN_DIM 128
#define HID 24
#define OUT_DIM 4096
#define NB 16384
#define KMOV 256

// ---------------- Kernel 1: transpose W3 [24,4096] -> W3T [4096,24] ----------
__global__ __launch_bounds__(256) void ktr(const float* __restrict__ W3,
                                           float* __restrict__ W3T) {
    int i = blockIdx.x * 256 + threadIdx.x;   // grid sized exactly
    int c = i / HID;
    int k = i - c * HID;
    W3T[i] = W3[k * OUT_DIM + c];             // W3T[c*24+k] = W3[k][c]
}

// ---------------- Kernel 2: fully fused MLP + masked softmax -----------------
// One block per batch row. Per block: stage W1/W2/x-row in LDS (L2-hot, ~7us
// aggregate, hidden under the 256MB write), compute h1/h2 in wave 0, then the
// constant-fill + scatter softmax (only <=256 move logits ever computed).
__global__ __launch_bounds__(256) void kfused(const float* __restrict__ x,
                                              const float* __restrict__ W1,
                                              const float* __restrict__ b1,
                                              const float* __restrict__ W2,
                                              const float* __restrict__ b2,
                                              const float* __restrict__ b3,
                                              const float* __restrict__ W3T,
                                              const int* __restrict__ moves,
                                              float* __restrict__ out) {
    __shared__ float W1s[IN_DIM * HID];        // 12 KB
    __shared__ float W2s[HID * HID];           // 2.3 KB
    __shared__ float xs[IN_DIM];               // 0.5 KB
    __shared__ float b1s[HID], b2s[HID], h2s[HID];
    __shared__ unsigned char claimed[OUT_DIM]; // 4 KB; no init: only written slots read
    __shared__ float red[8];

    int r = blockIdx.x;
    int t = threadIdx.x;

    // ---- stage (all coalesced / float4) ----
    {
        float4* W1v = (float4*)W1s;
        const float4* W1g = (const float4*)W1;     // 3072 floats = 768 float4
        #pragma unroll
        for (int i = 0; i < 3; i++) W1v[t + i * 256] = W1g[t + i * 256];
        if (t < 144) ((float4*)W2s)[t] = ((const float4*)W2)[t];  // 576 floats
        if (t < IN_DIM) xs[t] = x[(size_t)r * IN_DIM + t];
        if (t < HID) { b1s[t] = b1[t]; b2s[t] = b2[t]; }
    }
    int c = moves[(size_t)r * KMOV + t];
    __syncthreads();

    // ---- MLP for this row, in wave 0 lanes 0..31 ----
    if (t < 32) {
        float h1 = 0.f;
        if (t < HID) {
            h1 = b1s[t];
            #pragma unroll 8
            for (int i = 0; i < IN_DIM; i++) h1 += xs[i] * W1s[i * HID + t];
            h1 = fmaxf(h1, 0.f);
        }
        float h2 = (t < HID) ? b2s[t] : 0.f;
        #pragma unroll
        for (int k = 0; k < HID; k++) {
            float hk = __shfl(h1, k, 32);          // broadcast within lanes 0..31
            if (t < HID) h2 += hk * W2s[k * HID + t];
        }
        if (t < HID) h2s[t] = fmaxf(h2, 0.f);
    }
    __syncthreads();

    // ---- gather W3T column (24 contiguous floats), dot24 -> logit ----
    const float4* w = (const float4*)(W3T + c * HID);
    float4 a0 = w[0], a1 = w[1], a2 = w[2], a3 = w[3], a4 = w[4], a5 = w[5];
    float acc = b3[c];
    acc += a0.x*h2s[0] + a0.y*h2s[1] + a0.z*h2s[2]  + a0.w*h2s[3];
    acc += a1.x*h2s[4] + a1.y*h2s[5] + a1.z*h2s[6]  + a1.w*h2s[7];
    acc += a2.x*h2s[8] + a2.y*h2s[9] + a2.z*h2s[10] + a2.w*h2s[11];
    acc += a3.x*h2s[12]+ a3.y*h2s[13]+ a3.z*h2s[14] + a3.w*h2s[15];
    acc += a4.x*h2s[16]+ a4.y*h2s[17]+ a4.z*h2s[18] + a4.w*h2s[19];
    acc += a5.x*h2s[20]+ a5.y*h2s[21]+ a5.z*h2s[22] + a5.w*h2s[23];

    // claim slot c (any single writer wins; every reader of claimed[c] wrote it;
    // duplicates produce bitwise-identical e, so winner identity is irrelevant)
    claimed[c] = (unsigned char)t;

    // ---- block max of logits ----
    float m = acc;
    #pragma unroll
    for (int off = 32; off > 0; off >>= 1) m = fmaxf(m, __shfl_xor(m, off, 64));
    int wid = t >> 6;
    if ((t & 63) == 0) red[wid] = m;
    __syncthreads();   // orders claimed[] writes AND red[0..3]
    float mm = fmaxf(fmaxf(fmaxf(red[0], red[1]), fmaxf(red[2], red[3])), 0.f);

    float e      = __expf(acc - mm);   // native v_exp_f32
    float base_e = __expf(-mm);

    // ---- denominator with duplicates counted once ----
    float contrib = (claimed[c] == (unsigned char)t) ? (e - base_e) : 0.f;
    float s = contrib;
    #pragma unroll
    for (int off = 32; off > 0; off >>= 1) s += __shfl_xor(s, off, 64);
    if ((t & 63) == 0) red[4 + wid] = s;
    __syncthreads();
    float denom = (float)OUT_DIM * base_e + (red[4] + red[5] + red[6] + red[7]);
    float inv = 1.0f / denom;
    float oc  = base_e * inv;

    // ---- stream the per-row constant (coalesced float4) ----
    float4 ocv = make_float4(oc, oc, oc, oc);
    float4* out4 = (float4*)(out + (size_t)r * OUT_DIM);
    #pragma unroll
    for (int i = 0; i < 4; i++) out4[t + i * 256] = ocv;

    __syncthreads();   // drains vmcnt: fills complete before scatter overwrites

    // ---- scatter move probabilities (duplicates write identical values) ----
    out[(size_t)r * OUT_DIM + c] = e * inv;
}

extern "C" void kernel_launch(void* const* d_in, const int* in_sizes, int n_in,
                              void* d_out, int out_size, void* d_ws, size_t ws_size,
                              hipStream_t stream) {
    const float* x     = (const float*)d_in[0];
    const int*   moves = (const int*)  d_in[1];
    const float* W1    = (const float*)d_in[2];
    const float* b1    = (const float*)d_in[3];
    const float* W2    = (const float*)d_in[4];
    const float* b2    = (const float*)d_in[5];
    const float* W3    = (const float*)d_in[6];
    const float* b3    = (const float*)d_in[7];
    float* out = (float*)d_out;

    float* W3T = (float*)d_ws;    // 384 KB scratch

    ktr<<<(OUT_DIM * HID) / 256, 256, 0, stream>>>(W3, W3T);
    kfused<<<NB, 256, 0, stream>>>(x, W1, b1, W2, b2, b3, W3T, moves, out);
}

// Round 7
// 335.627 us; speedup vs baseline: 1.0438x; 1.0438x over previous
//
#include <hip/hip_runtime.h>
#include <hip/hip_bf16.h>

#define IN_DIM 128
#define HID 24
#define OUT_DIM 4096
#define NB 16384
#define KMOV 256

// ---------------- Kernel 1: transpose W3 [24,4096] -> W3T [4096,24] ----------
__global__ __launch_bounds__(256) void ktr(const float* __restrict__ W3,
                                           float* __restrict__ W3T) {
    int i = blockIdx.x * 256 + threadIdx.x;   // grid sized exactly
    int c = i / HID;
    int k = i - c * HID;
    W3T[i] = W3[k * OUT_DIM + c];             // W3T[c*24+k] = W3[k][c]
}

// ---------------- Kernel 2: fused MLP + masked softmax, LDS-assembled row ----
// One block per batch row. The output row is assembled ENTIRELY in LDS
// (constant fill + in-LDS scatter of move probs), then streamed to global in
// one pass: every 64B line is written exactly once, full — no partial-line
// global writes, no L2-evicted RMW traffic.
// LDS phase-aliasing (barrier-separated): [0,16KB) = W1/W2/x/b staging ->
// claimed[] -> probs[].
__global__ __launch_bounds__(256) void kfused(const float* __restrict__ x,
                                              const float* __restrict__ W1,
                                              const float* __restrict__ b1,
                                              const float* __restrict__ W2,
                                              const float* __restrict__ b2,
                                              const float* __restrict__ b3,
                                              const float* __restrict__ W3T,
                                              const int* __restrict__ moves,
                                              float* __restrict__ out) {
    __shared__ __align__(16) char smem[OUT_DIM * 4];   // 16 KB union
    __shared__ float h2s[HID];
    __shared__ float red[8];

    float* W1s = (float*)smem;                    // [0, 12288)   phase 1-2
    float* W2s = (float*)(smem + 12288);          // [12288,14592) phase 1-2
    float* xs  = (float*)(smem + 14592);          // [14592,15104) phase 1-2
    float* b12 = (float*)(smem + 15104);          // b1[0:24) b2[24:48) phase 1-2
    unsigned char* claimed = (unsigned char*)smem;// [0,4096)     phase 3-4
    float* probs = (float*)smem;                  // [0,16384)    phase 5

    int r = blockIdx.x;
    int t = threadIdx.x;

    // ---- phase 1: stage (all coalesced float4) ----
    {
        float4* W1v = (float4*)W1s;
        const float4* W1g = (const float4*)W1;    // 3072 floats = 768 float4
        W1v[t] = W1g[t];
        W1v[t + 256] = W1g[t + 256];
        W1v[t + 512] = W1g[t + 512];
        if (t < 144) ((float4*)W2s)[t] = ((const float4*)W2)[t];   // 576 floats
        if (t < 32)  ((float4*)xs)[t] = ((const float4*)(x + (size_t)r * IN_DIM))[t];
        if (t < HID) { b12[t] = b1[t]; b12[HID + t] = b2[t]; }
    }
    int c = moves[(size_t)r * KMOV + t];
    __syncthreads();

    // ---- phase 2: MLP for this row, wave 0 lanes 0..31 ----
    if (t < 32) {
        float h1 = 0.f;
        if (t < HID) {
            h1 = b12[t];
            #pragma unroll 8
            for (int i = 0; i < IN_DIM; i++) h1 += xs[i] * W1s[i * HID + t];
            h1 = fmaxf(h1, 0.f);
        }
        float h2 = (t < HID) ? b12[HID + t] : 0.f;
        #pragma unroll
        for (int k = 0; k < HID; k++) {
            float hk = __shfl(h1, k, 32);         // broadcast within lanes 0..31
            if (t < HID) h2 += hk * W2s[k * HID + t];
        }
        if (t < HID) h2s[t] = fmaxf(h2, 0.f);
    }
    __syncthreads();   // staging region dead from here; claimed may overlay it

    // ---- phase 3: gather W3T column (24 contiguous floats), dot24 -> logit --
    const float4* w = (const float4*)(W3T + c * HID);
    float4 a0 = w[0], a1 = w[1], a2 = w[2], a3 = w[3], a4 = w[4], a5 = w[5];
    float acc = b3[c];
    acc += a0.x*h2s[0] + a0.y*h2s[1] + a0.z*h2s[2]  + a0.w*h2s[3];
    acc += a1.x*h2s[4] + a1.y*h2s[5] + a1.z*h2s[6]  + a1.w*h2s[7];
    acc += a2.x*h2s[8] + a2.y*h2s[9] + a2.z*h2s[10] + a2.w*h2s[11];
    acc += a3.x*h2s[12]+ a3.y*h2s[13]+ a3.z*h2s[14] + a3.w*h2s[15];
    acc += a4.x*h2s[16]+ a4.y*h2s[17]+ a4.z*h2s[18] + a4.w*h2s[19];
    acc += a5.x*h2s[20]+ a5.y*h2s[21]+ a5.z*h2s[22] + a5.w*h2s[23];

    // claim slot c (any winner; duplicates produce bitwise-identical e anyway)
    claimed[c] = (unsigned char)t;

    // ---- block max of logits ----
    float m = acc;
    #pragma unroll
    for (int off = 32; off > 0; off >>= 1) m = fmaxf(m, __shfl_xor(m, off, 64));
    int wid = t >> 6;
    if ((t & 63) == 0) red[wid] = m;
    __syncthreads();   // orders claimed[] writes AND red[0..3]
    float mm = fmaxf(fmaxf(fmaxf(red[0], red[1]), fmaxf(red[2], red[3])), 0.f);

    float e      = __expf(acc - mm);   // native v_exp_f32
    float base_e = __expf(-mm);

    // ---- phase 4: denominator with duplicates counted once ----
    float contrib = (claimed[c] == (unsigned char)t) ? (e - base_e) : 0.f;
    float s = contrib;
    #pragma unroll
    for (int off = 32; off > 0; off >>= 1) s += __shfl_xor(s, off, 64);
    if ((t & 63) == 0) red[4 + wid] = s;
    __syncthreads();   // claimed reads complete; probs may overlay from here
    float denom = (float)OUT_DIM * base_e + (red[4] + red[5] + red[6] + red[7]);
    float inv = 1.0f / denom;
    float oc  = base_e * inv;
    float pm  = e * inv;

    // ---- phase 5: assemble full row in LDS ----
    float4* p4 = (float4*)probs;
    float4 ocv = make_float4(oc, oc, oc, oc);
    #pragma unroll
    for (int i = 0; i < 4; i++) p4[t + i * 256] = ocv;
    __syncthreads();
    probs[c] = pm;     // in-LDS scatter (duplicates write identical bits)
    __syncthreads();

    // ---- single streaming write pass: full 64B lines only ----
    float4* out4 = (float4*)(out + (size_t)r * OUT_DIM);
    #pragma unroll
    for (int i = 0; i < 4; i++) out4[t + i * 256] = p4[t + i * 256];
}

extern "C" void kernel_launch(void* const* d_in, const int* in_sizes, int n_in,
                              void* d_out, int out_size, void* d_ws, size_t ws_size,
                              hipStream_t stream) {
    const float* x     = (const float*)d_in[0];
    const int*   moves = (const int*)  d_in[1];
    const float* W1    = (const float*)d_in[2];
    const float* b1    = (const float*)d_in[3];
    const float* W2    = (const float*)d_in[4];
    const float* b2    = (const float*)d_in[5];
    const float* W3    = (const float*)d_in[6];
    const float* b3    = (const float*)d_in[7];
    float* out = (float*)d_out;

    float* W3T = (float*)d_ws;    // 384 KB scratch

    ktr<<<(OUT_DIM * HID) / 256, 256, 0, stream>>>(W3, W3T);
    kfused<<<NB, 256, 0, stream>>>(x, W1, b1, W2, b2, b3, W3T, moves, out);
}